// Round 1
// baseline (32033.810 us; speedup 1.0000x reference)
//
#include <hip/hip_runtime.h>
#include <stdint.h>

#define DD 256

// ---------------- Threefry-2x32 (bit-exact JAX) ----------------
__host__ __device__ __forceinline__ uint32_t rotl32(uint32_t v, int r) {
  return (v << r) | (v >> (32 - r));
}

__host__ __device__ inline void tf2x32(uint32_t k0, uint32_t k1,
                                       uint32_t& x0, uint32_t& x1) {
  uint32_t ks0 = k0, ks1 = k1, ks2 = k0 ^ k1 ^ 0x1BD11BDAu;
  x0 += ks0; x1 += ks1;
#define TF_RND(r) { x0 += x1; x1 = rotl32(x1, (r)); x1 ^= x0; }
  TF_RND(13) TF_RND(15) TF_RND(26) TF_RND(6)
  x0 += ks1; x1 += ks2 + 1u;
  TF_RND(17) TF_RND(29) TF_RND(16) TF_RND(24)
  x0 += ks2; x1 += ks0 + 2u;
  TF_RND(13) TF_RND(15) TF_RND(26) TF_RND(6)
  x0 += ks0; x1 += ks1 + 3u;
  TF_RND(17) TF_RND(29) TF_RND(16) TF_RND(24)
  x0 += ks1; x1 += ks2 + 4u;
  TF_RND(13) TF_RND(15) TF_RND(26) TF_RND(6)
  x0 += ks2; x1 += ks0 + 5u;
#undef TF_RND
}

// ---------------- init: x = p, out = p ----------------
__global__ void init_kernel(const float* __restrict__ p, float* __restrict__ x,
                            float* __restrict__ out, int total4) {
  int t4 = blockIdx.x * blockDim.x + threadIdx.x;
  if (t4 >= total4) return;
  float4 v = *((const float4*)p + t4);
  *((float4*)x + t4) = v;
  *((float4*)out + t4) = v;
}

// ---------------- COO SpMM, scatter-atomic, one wave per edge ----------------
__global__ void spmm_atomic(const int* __restrict__ rows, const int* __restrict__ cols,
                            const float* __restrict__ vals, const float* __restrict__ X,
                            float* __restrict__ Y, int nnz) {
  int gtid = blockIdx.x * blockDim.x + threadIdx.x;
  int wave = gtid >> 6;
  int lane = threadIdx.x & 63;
  int nw = (gridDim.x * blockDim.x) >> 6;
  for (int e = wave; e < nnz; e += nw) {
    int r = rows[e];
    int c = cols[e];
    float v = vals[e];
    float4 xv = *((const float4*)(X + (size_t)c * DD) + lane);
    float* y = Y + (size_t)r * DD + (size_t)lane * 4;
    __hip_atomic_fetch_add(y + 0, v * xv.x, __ATOMIC_RELAXED, __HIP_MEMORY_SCOPE_AGENT);
    __hip_atomic_fetch_add(y + 1, v * xv.y, __ATOMIC_RELAXED, __HIP_MEMORY_SCOPE_AGENT);
    __hip_atomic_fetch_add(y + 2, v * xv.z, __ATOMIC_RELAXED, __HIP_MEMORY_SCOPE_AGENT);
    __hip_atomic_fetch_add(y + 3, v * xv.w, __ATOMIC_RELAXED, __HIP_MEMORY_SCOPE_AGENT);
  }
}

// ---------------- dropout + residual + accumulate mean ----------------
// x_new = mask ? (s + x)/0.9 : 0 ; out += x_new ; (final: out *= 0.25)
// mask via JAX partitionable threefry: bits[j] = r0^r1, (r0,r1)=tf(key,(0,j))
__global__ void dropout_acc(const float* __restrict__ s, float* __restrict__ x,
                            float* __restrict__ out, uint32_t k0, uint32_t k1,
                            int total4, int is_final) {
  int t4 = blockIdx.x * blockDim.x + threadIdx.x;
  if (t4 >= total4) return;
  int j0 = t4 * 4;
  float4 sv = *((const float4*)(s + j0));
  float4 xv = *((const float4*)(x + j0));
  float4 ov = *((const float4*)(out + j0));
  float h[4] = {sv.x + xv.x, sv.y + xv.y, sv.z + xv.z, sv.w + xv.w};
  float xn[4];
#pragma unroll
  for (int k = 0; k < 4; ++k) {
    uint32_t r0 = 0u, r1 = (uint32_t)(j0 + k);
    tf2x32(k0, k1, r0, r1);
    uint32_t bits = r0 ^ r1;
    float u = __uint_as_float((bits >> 9) | 0x3f800000u) - 1.0f;
    xn[k] = (u < 0.9f) ? h[k] * (1.0f / 0.9f) : 0.0f;
  }
  *((float4*)(x + j0)) = make_float4(xn[0], xn[1], xn[2], xn[3]);
  float4 no = make_float4(ov.x + xn[0], ov.y + xn[1], ov.z + xn[2], ov.w + xn[3]);
  if (is_final) { no.x *= 0.25f; no.y *= 0.25f; no.z *= 0.25f; no.w *= 0.25f; }
  *((float4*)(out + j0)) = no;
}

extern "C" void kernel_launch(void* const* d_in, const int* in_sizes, int n_in,
                              void* d_out, int out_size, void* d_ws, size_t ws_size,
                              hipStream_t stream) {
  const float* p     = (const float*)d_in[0];
  const int*   s_row = (const int*)d_in[1];
  const int*   s_col = (const int*)d_in[2];
  const float* s_val = (const float*)d_in[3];
  const int*   t_row = (const int*)d_in[4];
  const int*   t_col = (const int*)d_in[5];
  const float* t_val = (const float*)d_in[6];

  const int nnz = in_sizes[1];
  const int N = in_sizes[0] / DD;   // 50000 pois
  const int H = 50000;              // num_hyperedges (problem constant)
  const size_t matN = (size_t)N * DD;
  const size_t matH = (size_t)H * DD;

  float* x = (float*)d_ws;          // [N, D] current layer input
  float* t = x + matN;              // [H, D] msg_tar
  float* s = t + matH;              // [N, D] msg_src
  float* out = (float*)d_out;       // [N, D] running sum of finals

  const int total4 = (int)(matN / 4);
  const int ew_blocks = (total4 + 255) / 256;

  init_kernel<<<ew_blocks, 256, 0, stream>>>(p, x, out, total4);

  const int spmm_blocks = 2048, spmm_threads = 256;

  for (int i = 0; i < 3; ++i) {
    hipMemsetAsync(t, 0, matH * sizeof(float), stream);
    spmm_atomic<<<spmm_blocks, spmm_threads, 0, stream>>>(t_row, t_col, t_val, x, t, nnz);
    hipMemsetAsync(s, 0, matN * sizeof(float), stream);
    spmm_atomic<<<spmm_blocks, spmm_threads, 0, stream>>>(s_row, s_col, s_val, t, s, nnz);
    // layer key: fold_in(key(42), i) = threefry2x32((0,42),(0,i))
    uint32_t x0 = 0u, x1 = (uint32_t)i;
    tf2x32(0u, 42u, x0, x1);
    dropout_acc<<<ew_blocks, 256, 0, stream>>>(s, x, out, x0, x1, total4, i == 2);
  }
}

// Round 2
// 1819.359 us; speedup vs baseline: 17.6072x; 17.6072x over previous
//
#include <hip/hip_runtime.h>
#include <stdint.h>

#define DD 256

// ---------------- Threefry-2x32 (bit-exact JAX) ----------------
__host__ __device__ __forceinline__ uint32_t rotl32(uint32_t v, int r) {
  return (v << r) | (v >> (32 - r));
}

__host__ __device__ inline void tf2x32(uint32_t k0, uint32_t k1,
                                       uint32_t& x0, uint32_t& x1) {
  uint32_t ks0 = k0, ks1 = k1, ks2 = k0 ^ k1 ^ 0x1BD11BDAu;
  x0 += ks0; x1 += ks1;
#define TF_RND(r) { x0 += x1; x1 = rotl32(x1, (r)); x1 ^= x0; }
  TF_RND(13) TF_RND(15) TF_RND(26) TF_RND(6)
  x0 += ks1; x1 += ks2 + 1u;
  TF_RND(17) TF_RND(29) TF_RND(16) TF_RND(24)
  x0 += ks2; x1 += ks0 + 2u;
  TF_RND(13) TF_RND(15) TF_RND(26) TF_RND(6)
  x0 += ks0; x1 += ks1 + 3u;
  TF_RND(17) TF_RND(29) TF_RND(16) TF_RND(24)
  x0 += ks1; x1 += ks2 + 4u;
  TF_RND(13) TF_RND(15) TF_RND(26) TF_RND(6)
  x0 += ks2; x1 += ks0 + 5u;
#undef TF_RND
}

// ---------------- init: x = p, out = p ----------------
__global__ void init_kernel(const float* __restrict__ p, float* __restrict__ x,
                            float* __restrict__ out, int total4) {
  int t4 = blockIdx.x * blockDim.x + threadIdx.x;
  if (t4 >= total4) return;
  float4 v = *((const float4*)p + t4);
  *((float4*)x + t4) = v;
  *((float4*)out + t4) = v;
}

// ---------------- CSR build: histogram, scan, scatter ----------------
__global__ void hist_kernel(const int* __restrict__ rows, int* __restrict__ cnt, int nnz) {
  int e = blockIdx.x * blockDim.x + threadIdx.x;
  if (e < nnz) atomicAdd(&cnt[rows[e]], 1);
}

// Two independent exclusive scans, one per block (block 0: tar, block 1: src).
__global__ void exscan2(const int* __restrict__ cnt0, int* __restrict__ offs0, int n0,
                        const int* __restrict__ cnt1, int* __restrict__ offs1, int n1) {
  const int* cnt = blockIdx.x ? cnt1 : cnt0;
  int* offs = blockIdx.x ? offs1 : offs0;
  int n = blockIdx.x ? n1 : n0;
  __shared__ int sdata[1024];
  __shared__ int carry_s;
  int tid = threadIdx.x;
  if (tid == 0) carry_s = 0;
  __syncthreads();
  for (int base = 0; base < n; base += 1024) {
    int i = base + tid;
    int v = (i < n) ? cnt[i] : 0;
    sdata[tid] = v;
    __syncthreads();
    for (int off = 1; off < 1024; off <<= 1) {
      int tmp = (tid >= off) ? sdata[tid - off] : 0;
      __syncthreads();
      sdata[tid] += tmp;
      __syncthreads();
    }
    int carry = carry_s;
    if (i < n) offs[i] = carry + sdata[tid] - v;   // exclusive
    __syncthreads();
    if (tid == 1023) carry_s = carry + sdata[1023];
    __syncthreads();
  }
  if (tid == 0) offs[n] = carry_s;
}

__global__ void scatter_kernel(const int* __restrict__ rows, const int* __restrict__ cols,
                               const float* __restrict__ vals, const int* __restrict__ offs,
                               int* __restrict__ cursor, int* __restrict__ ecols,
                               float* __restrict__ evals, int nnz) {
  int e = blockIdx.x * blockDim.x + threadIdx.x;
  if (e >= nnz) return;
  int r = rows[e];
  int pos = offs[r] + atomicAdd(&cursor[r], 1);
  ecols[pos] = cols[e];
  evals[pos] = vals[e];
}

// ---------------- gather SpMM: one wave per row, lane holds float4 ----------------
__global__ void spmm_csr(const int* __restrict__ offs, const int* __restrict__ ecols,
                         const float* __restrict__ evals, const float* __restrict__ X,
                         float* __restrict__ Y, int nrows) {
  int wid = threadIdx.x >> 6;
  int lane = threadIdx.x & 63;
  int r = blockIdx.x * 4 + wid;
  if (r >= nrows) return;
  int b = offs[r], e = offs[r + 1];
  const float4* Xv = (const float4*)X;
  float4 acc = make_float4(0.f, 0.f, 0.f, 0.f);
  int i = b;
  for (; i + 1 < e; i += 2) {
    int c0 = ecols[i], c1 = ecols[i + 1];
    float v0 = evals[i], v1 = evals[i + 1];
    float4 a0 = Xv[(size_t)c0 * 64 + lane];
    float4 a1 = Xv[(size_t)c1 * 64 + lane];
    acc.x += v0 * a0.x + v1 * a1.x;
    acc.y += v0 * a0.y + v1 * a1.y;
    acc.z += v0 * a0.z + v1 * a1.z;
    acc.w += v0 * a0.w + v1 * a1.w;
  }
  if (i < e) {
    int c0 = ecols[i];
    float v0 = evals[i];
    float4 a0 = Xv[(size_t)c0 * 64 + lane];
    acc.x += v0 * a0.x; acc.y += v0 * a0.y; acc.z += v0 * a0.z; acc.w += v0 * a0.w;
  }
  ((float4*)Y)[(size_t)r * 64 + lane] = acc;
}

// ---------------- gather SpMM + residual + dropout + mean-accumulate ----------------
__global__ void spmm_csr_dropout(const int* __restrict__ offs, const int* __restrict__ ecols,
                                 const float* __restrict__ evals, const float* __restrict__ T,
                                 float* __restrict__ x, float* __restrict__ out,
                                 uint32_t k0, uint32_t k1, int nrows, int is_final) {
  int wid = threadIdx.x >> 6;
  int lane = threadIdx.x & 63;
  int r = blockIdx.x * 4 + wid;
  if (r >= nrows) return;
  int b = offs[r], e = offs[r + 1];
  const float4* Tv = (const float4*)T;
  float4 acc = make_float4(0.f, 0.f, 0.f, 0.f);
  int i = b;
  for (; i + 1 < e; i += 2) {
    int c0 = ecols[i], c1 = ecols[i + 1];
    float v0 = evals[i], v1 = evals[i + 1];
    float4 a0 = Tv[(size_t)c0 * 64 + lane];
    float4 a1 = Tv[(size_t)c1 * 64 + lane];
    acc.x += v0 * a0.x + v1 * a1.x;
    acc.y += v0 * a0.y + v1 * a1.y;
    acc.z += v0 * a0.z + v1 * a1.z;
    acc.w += v0 * a0.w + v1 * a1.w;
  }
  if (i < e) {
    int c0 = ecols[i];
    float v0 = evals[i];
    float4 a0 = Tv[(size_t)c0 * 64 + lane];
    acc.x += v0 * a0.x; acc.y += v0 * a0.y; acc.z += v0 * a0.z; acc.w += v0 * a0.w;
  }
  size_t idx4 = (size_t)r * 64 + lane;
  float4 xv = ((const float4*)x)[idx4];
  float h[4] = {acc.x + xv.x, acc.y + xv.y, acc.z + xv.z, acc.w + xv.w};
  int j0 = r * DD + lane * 4;
  float xn[4];
#pragma unroll
  for (int k = 0; k < 4; ++k) {
    uint32_t r0 = 0u, r1 = (uint32_t)(j0 + k);
    tf2x32(k0, k1, r0, r1);
    uint32_t bits = r0 ^ r1;
    float u = __uint_as_float((bits >> 9) | 0x3f800000u) - 1.0f;
    xn[k] = (u < 0.9f) ? h[k] * (1.0f / 0.9f) : 0.0f;
  }
  ((float4*)x)[idx4] = make_float4(xn[0], xn[1], xn[2], xn[3]);
  float4 ov = ((const float4*)out)[idx4];
  float4 no = make_float4(ov.x + xn[0], ov.y + xn[1], ov.z + xn[2], ov.w + xn[3]);
  if (is_final) { no.x *= 0.25f; no.y *= 0.25f; no.z *= 0.25f; no.w *= 0.25f; }
  ((float4*)out)[idx4] = no;
}

extern "C" void kernel_launch(void* const* d_in, const int* in_sizes, int n_in,
                              void* d_out, int out_size, void* d_ws, size_t ws_size,
                              hipStream_t stream) {
  const float* p     = (const float*)d_in[0];
  const int*   s_row = (const int*)d_in[1];
  const int*   s_col = (const int*)d_in[2];
  const float* s_val = (const float*)d_in[3];
  const int*   t_row = (const int*)d_in[4];
  const int*   t_col = (const int*)d_in[5];
  const float* t_val = (const float*)d_in[6];

  const int nnz_s = in_sizes[1];
  const int nnz_t = in_sizes[4];
  const int N = in_sizes[0] / DD;   // 50000 pois
  const int H = 50000;              // num_hyperedges (problem constant)
  const size_t matN = (size_t)N * DD;
  const size_t matH = (size_t)H * DD;

  // ---- workspace carve ----
  float* x       = (float*)d_ws;            // [N,D]
  float* t       = x + matN;                // [H,D]
  int*   ecols_t = (int*)(t + matH);        // [nnz_t]
  float* evals_t = (float*)(ecols_t + nnz_t);
  int*   ecols_s = (int*)(evals_t + nnz_t); // [nnz_s]
  float* evals_s = (float*)(ecols_s + nnz_s);
  int*   offs_t  = (int*)(evals_s + nnz_s); // [H+1]
  int*   offs_s  = offs_t + (H + 1);        // [N+1]
  int*   cnt_t   = offs_s + (N + 1);        // [H]
  int*   cnt_s   = cnt_t + H;               // [N]
  int*   cur_t   = cnt_s + N;               // [H]
  int*   cur_s   = cur_t + H;               // [N]

  float* out = (float*)d_out;

  // ---- CSR build (both matrices) ----
  hipMemsetAsync(cnt_t, 0, sizeof(int) * (size_t)(2 * H + 2 * N), stream);
  {
    int hb_t = (nnz_t + 255) / 256, hb_s = (nnz_s + 255) / 256;
    hist_kernel<<<hb_t, 256, 0, stream>>>(t_row, cnt_t, nnz_t);
    hist_kernel<<<hb_s, 256, 0, stream>>>(s_row, cnt_s, nnz_s);
    exscan2<<<2, 1024, 0, stream>>>(cnt_t, offs_t, H, cnt_s, offs_s, N);
    scatter_kernel<<<hb_t, 256, 0, stream>>>(t_row, t_col, t_val, offs_t, cur_t,
                                             ecols_t, evals_t, nnz_t);
    scatter_kernel<<<hb_s, 256, 0, stream>>>(s_row, s_col, s_val, offs_s, cur_s,
                                             ecols_s, evals_s, nnz_s);
  }

  // ---- init ----
  const int total4 = (int)(matN / 4);
  init_kernel<<<(total4 + 255) / 256, 256, 0, stream>>>(p, x, out, total4);

  // ---- 3 layers ----
  for (int i = 0; i < 3; ++i) {
    spmm_csr<<<(H + 3) / 4, 256, 0, stream>>>(offs_t, ecols_t, evals_t, x, t, H);
    uint32_t x0 = 0u, x1 = (uint32_t)i;
    tf2x32(0u, 42u, x0, x1);
    spmm_csr_dropout<<<(N + 3) / 4, 256, 0, stream>>>(offs_s, ecols_s, evals_s, t,
                                                      x, out, x0, x1, N, i == 2);
  }
}

// Round 3
// 1787.862 us; speedup vs baseline: 17.9174x; 1.0176x over previous
//
#include <hip/hip_runtime.h>
#include <stdint.h>

#define DD 256
#define TILE_SHIFT 11          // 2048 cols per tile = 2 MB of X rows
#define NT 25                  // ceil(50000 / 2048)

// ---------------- Threefry-2x32 (bit-exact JAX) ----------------
__host__ __device__ __forceinline__ uint32_t rotl32(uint32_t v, int r) {
  return (v << r) | (v >> (32 - r));
}

__host__ __device__ inline void tf2x32(uint32_t k0, uint32_t k1,
                                       uint32_t& x0, uint32_t& x1) {
  uint32_t ks0 = k0, ks1 = k1, ks2 = k0 ^ k1 ^ 0x1BD11BDAu;
  x0 += ks0; x1 += ks1;
#define TF_RND(r) { x0 += x1; x1 = rotl32(x1, (r)); x1 ^= x0; }
  TF_RND(13) TF_RND(15) TF_RND(26) TF_RND(6)
  x0 += ks1; x1 += ks2 + 1u;
  TF_RND(17) TF_RND(29) TF_RND(16) TF_RND(24)
  x0 += ks2; x1 += ks0 + 2u;
  TF_RND(13) TF_RND(15) TF_RND(26) TF_RND(6)
  x0 += ks0; x1 += ks1 + 3u;
  TF_RND(17) TF_RND(29) TF_RND(16) TF_RND(24)
  x0 += ks1; x1 += ks2 + 4u;
  TF_RND(13) TF_RND(15) TF_RND(26) TF_RND(6)
  x0 += ks2; x1 += ks0 + 5u;
#undef TF_RND
}

// ---------------- init: x = p, out = p ----------------
__global__ void init_kernel(const float* __restrict__ p, float* __restrict__ x,
                            float* __restrict__ out, int total4) {
  int t4 = blockIdx.x * blockDim.x + threadIdx.x;
  if (t4 >= total4) return;
  float4 v = *((const float4*)p + t4);
  *((float4*)x + t4) = v;
  *((float4*)out + t4) = v;
}

// ---------------- CSR build: (row,tile) histogram ----------------
__global__ void hist16(const int* __restrict__ rows, const int* __restrict__ cols,
                       int* __restrict__ cnt, int nnz, int row_base) {
  int e = blockIdx.x * blockDim.x + threadIdx.x;
  if (e >= nnz) return;
  int slot = (row_base + rows[e]) * NT + (cols[e] >> TILE_SHIFT);
  atomicAdd(&cnt[slot], 1);
}

// ---------------- hierarchical exclusive scan ----------------
// K1: per-block (2048 elems, 256 thr x 8) exclusive scan in-place + partial
__global__ void scan_block(int* __restrict__ data, int* __restrict__ partials, int len) {
  int base = blockIdx.x * 2048 + threadIdx.x * 8;
  int v[8];
#pragma unroll
  for (int k = 0; k < 8; ++k) { int i = base + k; v[k] = (i < len) ? data[i] : 0; }
  int tsum = 0;
#pragma unroll
  for (int k = 0; k < 8; ++k) { int tv = v[k]; v[k] = tsum; tsum += tv; }
  int lane = threadIdx.x & 63, wid = threadIdx.x >> 6;
  int inc = tsum;
  for (int off = 1; off < 64; off <<= 1) {
    int up = __shfl_up(inc, off, 64);
    if (lane >= off) inc += up;
  }
  __shared__ int wsum[4];
  if (lane == 63) wsum[wid] = inc;
  __syncthreads();
  int wbase = 0;
  for (int w = 0; w < wid; ++w) wbase += wsum[w];
  int texc = wbase + inc - tsum;
#pragma unroll
  for (int k = 0; k < 8; ++k) { int i = base + k; if (i < len) data[i] = texc + v[k]; }
  if (threadIdx.x == 255) partials[blockIdx.x] = texc + tsum;
}

// K2: one-block exclusive scan of partials (sequential 1024-chunks)
__global__ void scan_top(int* __restrict__ p, int n) {
  __shared__ int sdata[1024];
  __shared__ int carry_s;
  int tid = threadIdx.x;
  if (tid == 0) carry_s = 0;
  __syncthreads();
  for (int base = 0; base < n; base += 1024) {
    int i = base + tid;
    int v = (i < n) ? p[i] : 0;
    sdata[tid] = v;
    __syncthreads();
    for (int off = 1; off < 1024; off <<= 1) {
      int tmp = (tid >= off) ? sdata[tid - off] : 0;
      __syncthreads();
      sdata[tid] += tmp;
      __syncthreads();
    }
    int c = carry_s;
    if (i < n) p[i] = c + sdata[tid] - v;
    __syncthreads();
    if (tid == 1023) carry_s = c + sdata[1023];
    __syncthreads();
  }
}

// K3: add scanned partials back
__global__ void scan_addback(int* __restrict__ data, const int* __restrict__ partials, int len) {
  int base = blockIdx.x * 2048 + threadIdx.x * 8;
  int add = partials[blockIdx.x];
#pragma unroll
  for (int k = 0; k < 8; ++k) { int i = base + k; if (i < len) data[i] += add; }
}

// ---------------- scatter into tile-grouped CSR (cursor = offs itself) ----------------
__global__ void scatter16(const int* __restrict__ rows, const int* __restrict__ cols,
                          const float* __restrict__ vals, int* __restrict__ offs,
                          int2* __restrict__ epack, int nnz, int row_base) {
  int e = blockIdx.x * blockDim.x + threadIdx.x;
  if (e >= nnz) return;
  int c = cols[e];
  int slot = (row_base + rows[e]) * NT + (c >> TILE_SHIFT);
  int pos = atomicAdd(&offs[slot], 1);
  epack[pos] = make_int2(c, __float_as_int(vals[e]));
}

// After scatter: offs[slot] = end of slot. Row g's range:
//   b = (g == 0) ? 0 : offs[g*NT - 1];   e = offs[g*NT + NT - 1]
__device__ __forceinline__ void row_range(const int* offs, int g, int& b, int& e) {
  b = (g == 0) ? 0 : offs[g * NT - 1];
  e = offs[g * NT + NT - 1];
}

// ---------------- gather SpMM: one wave per row, lane holds float4 ----------------
__global__ void spmm_csr(const int* __restrict__ offs, const int2* __restrict__ ep,
                         const float* __restrict__ X, float* __restrict__ Y,
                         int nrows, int grow_base) {
  int wid = threadIdx.x >> 6;
  int lane = threadIdx.x & 63;
  int r = blockIdx.x * 4 + wid;
  if (r >= nrows) return;
  int b, e;
  row_range(offs, grow_base + r, b, e);
  const float4* Xv = (const float4*)X;
  float4 acc = make_float4(0.f, 0.f, 0.f, 0.f);
  int i = b;
  for (; i + 3 < e; i += 4) {
    int2 e0 = ep[i], e1 = ep[i + 1], e2 = ep[i + 2], e3 = ep[i + 3];
    float4 a0 = Xv[(size_t)e0.x * 64 + lane];
    float4 a1 = Xv[(size_t)e1.x * 64 + lane];
    float4 a2 = Xv[(size_t)e2.x * 64 + lane];
    float4 a3 = Xv[(size_t)e3.x * 64 + lane];
    float v0 = __int_as_float(e0.y), v1 = __int_as_float(e1.y);
    float v2 = __int_as_float(e2.y), v3 = __int_as_float(e3.y);
    acc.x += v0 * a0.x + v1 * a1.x + v2 * a2.x + v3 * a3.x;
    acc.y += v0 * a0.y + v1 * a1.y + v2 * a2.y + v3 * a3.y;
    acc.z += v0 * a0.z + v1 * a1.z + v2 * a2.z + v3 * a3.z;
    acc.w += v0 * a0.w + v1 * a1.w + v2 * a2.w + v3 * a3.w;
  }
  for (; i < e; ++i) {
    int2 e0 = ep[i];
    float4 a0 = Xv[(size_t)e0.x * 64 + lane];
    float v0 = __int_as_float(e0.y);
    acc.x += v0 * a0.x; acc.y += v0 * a0.y; acc.z += v0 * a0.z; acc.w += v0 * a0.w;
  }
  ((float4*)Y)[(size_t)r * 64 + lane] = acc;
}

// ---------------- gather SpMM + residual + dropout + mean-accumulate ----------------
__global__ void spmm_csr_dropout(const int* __restrict__ offs, const int2* __restrict__ ep,
                                 const float* __restrict__ T, float* __restrict__ x,
                                 float* __restrict__ out, uint32_t k0, uint32_t k1,
                                 int nrows, int grow_base, int is_final) {
  int wid = threadIdx.x >> 6;
  int lane = threadIdx.x & 63;
  int r = blockIdx.x * 4 + wid;
  if (r >= nrows) return;
  int b, e;
  row_range(offs, grow_base + r, b, e);
  const float4* Tv = (const float4*)T;
  float4 acc = make_float4(0.f, 0.f, 0.f, 0.f);
  int i = b;
  for (; i + 3 < e; i += 4) {
    int2 e0 = ep[i], e1 = ep[i + 1], e2 = ep[i + 2], e3 = ep[i + 3];
    float4 a0 = Tv[(size_t)e0.x * 64 + lane];
    float4 a1 = Tv[(size_t)e1.x * 64 + lane];
    float4 a2 = Tv[(size_t)e2.x * 64 + lane];
    float4 a3 = Tv[(size_t)e3.x * 64 + lane];
    float v0 = __int_as_float(e0.y), v1 = __int_as_float(e1.y);
    float v2 = __int_as_float(e2.y), v3 = __int_as_float(e3.y);
    acc.x += v0 * a0.x + v1 * a1.x + v2 * a2.x + v3 * a3.x;
    acc.y += v0 * a0.y + v1 * a1.y + v2 * a2.y + v3 * a3.y;
    acc.z += v0 * a0.z + v1 * a1.z + v2 * a2.z + v3 * a3.z;
    acc.w += v0 * a0.w + v1 * a1.w + v2 * a2.w + v3 * a3.w;
  }
  for (; i < e; ++i) {
    int2 e0 = ep[i];
    float4 a0 = Tv[(size_t)e0.x * 64 + lane];
    float v0 = __int_as_float(e0.y);
    acc.x += v0 * a0.x; acc.y += v0 * a0.y; acc.z += v0 * a0.z; acc.w += v0 * a0.w;
  }
  size_t idx4 = (size_t)r * 64 + lane;
  float4 xv = ((const float4*)x)[idx4];
  float h[4] = {acc.x + xv.x, acc.y + xv.y, acc.z + xv.z, acc.w + xv.w};
  int j0 = r * DD + lane * 4;
  float xn[4];
#pragma unroll
  for (int k = 0; k < 4; ++k) {
    uint32_t r0 = 0u, r1 = (uint32_t)(j0 + k);
    tf2x32(k0, k1, r0, r1);
    uint32_t bits = r0 ^ r1;
    float u = __uint_as_float((bits >> 9) | 0x3f800000u) - 1.0f;
    xn[k] = (u < 0.9f) ? h[k] * (1.0f / 0.9f) : 0.0f;
  }
  ((float4*)x)[idx4] = make_float4(xn[0], xn[1], xn[2], xn[3]);
  float4 ov = ((const float4*)out)[idx4];
  float4 no = make_float4(ov.x + xn[0], ov.y + xn[1], ov.z + xn[2], ov.w + xn[3]);
  if (is_final) { no.x *= 0.25f; no.y *= 0.25f; no.z *= 0.25f; no.w *= 0.25f; }
  ((float4*)out)[idx4] = no;
}

extern "C" void kernel_launch(void* const* d_in, const int* in_sizes, int n_in,
                              void* d_out, int out_size, void* d_ws, size_t ws_size,
                              hipStream_t stream) {
  const float* p     = (const float*)d_in[0];
  const int*   s_row = (const int*)d_in[1];
  const int*   s_col = (const int*)d_in[2];
  const float* s_val = (const float*)d_in[3];
  const int*   t_row = (const int*)d_in[4];
  const int*   t_col = (const int*)d_in[5];
  const float* t_val = (const float*)d_in[6];

  const int nnz_s = in_sizes[1];
  const int nnz_t = in_sizes[4];
  const int N = in_sizes[0] / DD;   // 50000 pois
  const int H = 50000;              // num_hyperedges (problem constant)
  const size_t matN = (size_t)N * DD;
  const size_t matH = (size_t)H * DD;

  // ---- workspace carve ----
  float* x     = (float*)d_ws;                       // [N,D]
  float* t     = x + matN;                           // [H,D]
  int2*  epack = (int2*)(t + matH);                  // [nnz_t + nnz_s]
  int*   offs  = (int*)(epack + (size_t)nnz_t + nnz_s); // [(H+N)*NT]
  const int slots = (H + N) * NT;                    // 2.5M
  int*   part  = offs + slots;                       // scan partials

  float* out = (float*)d_out;

  // ---- build tile-grouped CSR for both matrices in one table ----
  // t-matrix rows at global rows [0,H); s-matrix rows at [H, H+N)
  hipMemsetAsync(offs, 0, sizeof(int) * (size_t)slots, stream);
  const int hb_t = (nnz_t + 255) / 256, hb_s = (nnz_s + 255) / 256;
  hist16<<<hb_t, 256, 0, stream>>>(t_row, t_col, offs, nnz_t, 0);
  hist16<<<hb_s, 256, 0, stream>>>(s_row, s_col, offs, nnz_s, H);
  const int nscan_blocks = (slots + 2047) / 2048;
  scan_block<<<nscan_blocks, 256, 0, stream>>>(offs, part, slots);
  scan_top<<<1, 1024, 0, stream>>>(part, nscan_blocks);
  scan_addback<<<nscan_blocks, 256, 0, stream>>>(offs, part, slots);
  scatter16<<<hb_t, 256, 0, stream>>>(t_row, t_col, t_val, offs, epack, nnz_t, 0);
  scatter16<<<hb_s, 256, 0, stream>>>(s_row, s_col, s_val, offs, epack, nnz_s, H);

  // ---- init ----
  const int total4 = (int)(matN / 4);
  init_kernel<<<(total4 + 255) / 256, 256, 0, stream>>>(p, x, out, total4);

  // ---- 3 layers ----
  for (int i = 0; i < 3; ++i) {
    spmm_csr<<<(H + 3) / 4, 256, 0, stream>>>(offs, epack, x, t, H, 0);
    uint32_t x0 = 0u, x1 = (uint32_t)i;
    tf2x32(0u, 42u, x0, x1);
    spmm_csr_dropout<<<(N + 3) / 4, 256, 0, stream>>>(offs, epack, t, x, out,
                                                      x0, x1, N, H, i == 2);
  }
}

// Round 4
// 1150.589 us; speedup vs baseline: 27.8412x; 1.5539x over previous
//
#include <hip/hip_runtime.h>
#include <hip/hip_fp16.h>
#include <stdint.h>

#define DD 256

// ---------------- Threefry-2x32 (bit-exact JAX) ----------------
__host__ __device__ __forceinline__ uint32_t rotl32(uint32_t v, int r) {
  return (v << r) | (v >> (32 - r));
}

__host__ __device__ inline void tf2x32(uint32_t k0, uint32_t k1,
                                       uint32_t& x0, uint32_t& x1) {
  uint32_t ks0 = k0, ks1 = k1, ks2 = k0 ^ k1 ^ 0x1BD11BDAu;
  x0 += ks0; x1 += ks1;
#define TF_RND(r) { x0 += x1; x1 = rotl32(x1, (r)); x1 ^= x0; }
  TF_RND(13) TF_RND(15) TF_RND(26) TF_RND(6)
  x0 += ks1; x1 += ks2 + 1u;
  TF_RND(17) TF_RND(29) TF_RND(16) TF_RND(24)
  x0 += ks2; x1 += ks0 + 2u;
  TF_RND(13) TF_RND(15) TF_RND(26) TF_RND(6)
  x0 += ks0; x1 += ks1 + 3u;
  TF_RND(17) TF_RND(29) TF_RND(16) TF_RND(24)
  x0 += ks1; x1 += ks2 + 4u;
  TF_RND(13) TF_RND(15) TF_RND(26) TF_RND(6)
  x0 += ks2; x1 += ks0 + 5u;
#undef TF_RND
}

// ---------------- init: out = p (f32), x = p (fp16) ----------------
__global__ void init_kernel(const float* __restrict__ p, __half2* __restrict__ xh,
                            float* __restrict__ out, int total4) {
  int t4 = blockIdx.x * blockDim.x + threadIdx.x;
  if (t4 >= total4) return;
  float4 v = ((const float4*)p)[t4];
  ((float4*)out)[t4] = v;
  __half2 h0 = __floats2half2_rn(v.x, v.y);
  __half2 h1 = __floats2half2_rn(v.z, v.w);
  uint2 u;
  u.x = *(const uint32_t*)&h0;
  u.y = *(const uint32_t*)&h1;
  ((uint2*)xh)[t4] = u;
}

// ---------------- CSR build: per-row histogram ----------------
__global__ void hist_kernel(const int* __restrict__ rows, int* __restrict__ cnt,
                            int nnz, int row_base) {
  int e = blockIdx.x * blockDim.x + threadIdx.x;
  if (e < nnz) atomicAdd(&cnt[row_base + rows[e]], 1);
}

// ---------------- hierarchical exclusive scan ----------------
__global__ void scan_block(int* __restrict__ data, int* __restrict__ partials, int len) {
  int base = blockIdx.x * 2048 + threadIdx.x * 8;
  int v[8];
#pragma unroll
  for (int k = 0; k < 8; ++k) { int i = base + k; v[k] = (i < len) ? data[i] : 0; }
  int tsum = 0;
#pragma unroll
  for (int k = 0; k < 8; ++k) { int tv = v[k]; v[k] = tsum; tsum += tv; }
  int lane = threadIdx.x & 63, wid = threadIdx.x >> 6;
  int inc = tsum;
  for (int off = 1; off < 64; off <<= 1) {
    int up = __shfl_up(inc, off, 64);
    if (lane >= off) inc += up;
  }
  __shared__ int wsum[4];
  if (lane == 63) wsum[wid] = inc;
  __syncthreads();
  int wbase = 0;
  for (int w = 0; w < wid; ++w) wbase += wsum[w];
  int texc = wbase + inc - tsum;
#pragma unroll
  for (int k = 0; k < 8; ++k) { int i = base + k; if (i < len) data[i] = texc + v[k]; }
  if (threadIdx.x == 255) partials[blockIdx.x] = texc + tsum;
}

__global__ void scan_top(int* __restrict__ p, int n) {
  __shared__ int sdata[1024];
  __shared__ int carry_s;
  int tid = threadIdx.x;
  if (tid == 0) carry_s = 0;
  __syncthreads();
  for (int base = 0; base < n; base += 1024) {
    int i = base + tid;
    int v = (i < n) ? p[i] : 0;
    sdata[tid] = v;
    __syncthreads();
    for (int off = 1; off < 1024; off <<= 1) {
      int tmp = (tid >= off) ? sdata[tid - off] : 0;
      __syncthreads();
      sdata[tid] += tmp;
      __syncthreads();
    }
    int c = carry_s;
    if (i < n) p[i] = c + sdata[tid] - v;
    __syncthreads();
    if (tid == 1023) carry_s = c + sdata[1023];
    __syncthreads();
  }
}

__global__ void scan_addback(int* __restrict__ data, const int* __restrict__ partials, int len) {
  int base = blockIdx.x * 2048 + threadIdx.x * 8;
  int add = partials[blockIdx.x];
#pragma unroll
  for (int k = 0; k < 8; ++k) { int i = base + k; if (i < len) data[i] += add; }
}

// ---------------- scatter (cursor = offs itself; post-scatter offs[g]=row end) ----------------
__global__ void scatter_kernel(const int* __restrict__ rows, const int* __restrict__ cols,
                               const float* __restrict__ vals, int* __restrict__ offs,
                               int2* __restrict__ epack, int nnz, int row_base) {
  int e = blockIdx.x * blockDim.x + threadIdx.x;
  if (e >= nnz) return;
  int pos = atomicAdd(&offs[row_base + rows[e]], 1);
  epack[pos] = make_int2(cols[e], __float_as_int(vals[e]));
}

// block-id decode: dhalf from bid%8 quadrant (XCD-pinned D-halves), row-block dense
__device__ __forceinline__ void decode_bid(int bid, int& dh, int& rb) {
  dh = (bid >> 2) & 1;
  rb = (bid & 3) | ((bid >> 3) << 2);
}

// ---------------- gather SpMM (fp16 operand, half D per block) ----------------
__global__ void spmm_half(const int* __restrict__ offs, const int2* __restrict__ ep,
                          const __half2* __restrict__ X, __half2* __restrict__ Y,
                          int nrows, int grow_base) {
  int wid = threadIdx.x >> 6, lane = threadIdx.x & 63;
  int dh, rb;
  decode_bid(blockIdx.x, dh, rb);
  int r = rb * 4 + wid;
  if (r >= nrows) return;
  int g = grow_base + r;
  int b = (g == 0) ? 0 : offs[g - 1];
  int e = offs[g];
  int hoff = dh * 64 + lane;
  float2 acc = make_float2(0.f, 0.f);
  int i = b;
  for (; i + 3 < e; i += 4) {
    int2 e0 = ep[i], e1 = ep[i + 1], e2 = ep[i + 2], e3 = ep[i + 3];
    float2 a0 = __half22float2(X[(size_t)e0.x * 128 + hoff]);
    float2 a1 = __half22float2(X[(size_t)e1.x * 128 + hoff]);
    float2 a2 = __half22float2(X[(size_t)e2.x * 128 + hoff]);
    float2 a3 = __half22float2(X[(size_t)e3.x * 128 + hoff]);
    float v0 = __int_as_float(e0.y), v1 = __int_as_float(e1.y);
    float v2 = __int_as_float(e2.y), v3 = __int_as_float(e3.y);
    acc.x += v0 * a0.x + v1 * a1.x + v2 * a2.x + v3 * a3.x;
    acc.y += v0 * a0.y + v1 * a1.y + v2 * a2.y + v3 * a3.y;
  }
  for (; i < e; ++i) {
    int2 e0 = ep[i];
    float2 a0 = __half22float2(X[(size_t)e0.x * 128 + hoff]);
    float v0 = __int_as_float(e0.y);
    acc.x += v0 * a0.x; acc.y += v0 * a0.y;
  }
  Y[(size_t)r * 128 + hoff] = __floats2half2_rn(acc.x, acc.y);
}

// ---------------- gather SpMM + residual + dropout + mean-accumulate ----------------
__global__ void spmm_drop_half(const int* __restrict__ offs, const int2* __restrict__ ep,
                               const __half2* __restrict__ T, __half2* __restrict__ x,
                               float* __restrict__ out, uint32_t k0, uint32_t k1,
                               int nrows, int grow_base, int is_final) {
  int wid = threadIdx.x >> 6, lane = threadIdx.x & 63;
  int dh, rb;
  decode_bid(blockIdx.x, dh, rb);
  int r = rb * 4 + wid;
  if (r >= nrows) return;
  int g = grow_base + r;
  int b = (g == 0) ? 0 : offs[g - 1];
  int e = offs[g];
  int hoff = dh * 64 + lane;
  float2 acc = make_float2(0.f, 0.f);
  int i = b;
  for (; i + 3 < e; i += 4) {
    int2 e0 = ep[i], e1 = ep[i + 1], e2 = ep[i + 2], e3 = ep[i + 3];
    float2 a0 = __half22float2(T[(size_t)e0.x * 128 + hoff]);
    float2 a1 = __half22float2(T[(size_t)e1.x * 128 + hoff]);
    float2 a2 = __half22float2(T[(size_t)e2.x * 128 + hoff]);
    float2 a3 = __half22float2(T[(size_t)e3.x * 128 + hoff]);
    float v0 = __int_as_float(e0.y), v1 = __int_as_float(e1.y);
    float v2 = __int_as_float(e2.y), v3 = __int_as_float(e3.y);
    acc.x += v0 * a0.x + v1 * a1.x + v2 * a2.x + v3 * a3.x;
    acc.y += v0 * a0.y + v1 * a1.y + v2 * a2.y + v3 * a3.y;
  }
  for (; i < e; ++i) {
    int2 e0 = ep[i];
    float2 a0 = __half22float2(T[(size_t)e0.x * 128 + hoff]);
    float v0 = __int_as_float(e0.y);
    acc.x += v0 * a0.x; acc.y += v0 * a0.y;
  }
  size_t xi = (size_t)r * 128 + hoff;
  float2 xv = __half22float2(x[xi]);
  float h0 = acc.x + xv.x, h1 = acc.y + xv.y;
  int j0 = r * DD + dh * 128 + lane * 2;
  float xn0, xn1;
  {
    uint32_t r0 = 0u, r1 = (uint32_t)j0;
    tf2x32(k0, k1, r0, r1);
    uint32_t bits = r0 ^ r1;
    float u = __uint_as_float((bits >> 9) | 0x3f800000u) - 1.0f;
    xn0 = (u < 0.9f) ? h0 * (1.0f / 0.9f) : 0.0f;
  }
  {
    uint32_t r0 = 0u, r1 = (uint32_t)(j0 + 1);
    tf2x32(k0, k1, r0, r1);
    uint32_t bits = r0 ^ r1;
    float u = __uint_as_float((bits >> 9) | 0x3f800000u) - 1.0f;
    xn1 = (u < 0.9f) ? h1 * (1.0f / 0.9f) : 0.0f;
  }
  x[xi] = __floats2half2_rn(xn0, xn1);
  float2 ov = ((const float2*)out)[xi];
  ov.x += xn0; ov.y += xn1;
  if (is_final) { ov.x *= 0.25f; ov.y *= 0.25f; }
  ((float2*)out)[xi] = ov;
}

extern "C" void kernel_launch(void* const* d_in, const int* in_sizes, int n_in,
                              void* d_out, int out_size, void* d_ws, size_t ws_size,
                              hipStream_t stream) {
  const float* p     = (const float*)d_in[0];
  const int*   s_row = (const int*)d_in[1];
  const int*   s_col = (const int*)d_in[2];
  const float* s_val = (const float*)d_in[3];
  const int*   t_row = (const int*)d_in[4];
  const int*   t_col = (const int*)d_in[5];
  const float* t_val = (const float*)d_in[6];

  const int nnz_s = in_sizes[1];
  const int nnz_t = in_sizes[4];
  const int N = in_sizes[0] / DD;   // 50000 pois
  const int H = 50000;              // num_hyperedges (problem constant)

  // ---- workspace carve ----
  __half2* xh    = (__half2*)d_ws;                       // [N*128] half2
  __half2* th    = xh + (size_t)N * 128;                 // [H*128] half2
  int2*    epack = (int2*)(th + (size_t)H * 128);        // [nnz_t + nnz_s]
  int*     offs  = (int*)(epack + (size_t)nnz_t + nnz_s);// [H+N] (t rows then s rows)
  const int slots = H + N;
  int*     part  = offs + slots;

  float* out = (float*)d_out;

  // ---- CSR build (both matrices share one offset table) ----
  hipMemsetAsync(offs, 0, sizeof(int) * (size_t)slots, stream);
  const int hb_t = (nnz_t + 255) / 256, hb_s = (nnz_s + 255) / 256;
  hist_kernel<<<hb_t, 256, 0, stream>>>(t_row, offs, nnz_t, 0);
  hist_kernel<<<hb_s, 256, 0, stream>>>(s_row, offs, nnz_s, H);
  const int nscan_blocks = (slots + 2047) / 2048;
  scan_block<<<nscan_blocks, 256, 0, stream>>>(offs, part, slots);
  scan_top<<<1, 1024, 0, stream>>>(part, nscan_blocks);
  scan_addback<<<nscan_blocks, 256, 0, stream>>>(offs, part, slots);
  scatter_kernel<<<hb_t, 256, 0, stream>>>(t_row, t_col, t_val, offs, epack, nnz_t, 0);
  scatter_kernel<<<hb_s, 256, 0, stream>>>(s_row, s_col, s_val, offs, epack, nnz_s, H);

  // ---- init ----
  const int total4 = N * DD / 4;
  init_kernel<<<(total4 + 255) / 256, 256, 0, stream>>>(p, xh, out, total4);

  // ---- 3 layers ----
  const int RB_H = (((H + 3) / 4 + 3) & ~3);
  const int RB_N = (((N + 3) / 4 + 3) & ~3);
  for (int i = 0; i < 3; ++i) {
    spmm_half<<<2 * RB_H, 256, 0, stream>>>(offs, epack, xh, th, H, 0);
    uint32_t x0 = 0u, x1 = (uint32_t)i;
    tf2x32(0u, 42u, x0, x1);
    spmm_drop_half<<<2 * RB_N, 256, 0, stream>>>(offs, epack, th, xh, out,
                                                 x0, x1, N, H, i == 2);
  }
}

// Round 6
// 1128.700 us; speedup vs baseline: 28.3812x; 1.0194x over previous
//
#include <hip/hip_runtime.h>
#include <hip/hip_fp16.h>
#include <stdint.h>

#define DD 256

// ext_vector types accepted by __builtin_nontemporal_*
typedef float  fx4 __attribute__((ext_vector_type(4)));
typedef uint32_t ux2 __attribute__((ext_vector_type(2)));
typedef int    ix2 __attribute__((ext_vector_type(2)));

// ---------------- Threefry-2x32 (bit-exact JAX) ----------------
__host__ __device__ __forceinline__ uint32_t rotl32(uint32_t v, int r) {
  return (v << r) | (v >> (32 - r));
}

__host__ __device__ inline void tf2x32(uint32_t k0, uint32_t k1,
                                       uint32_t& x0, uint32_t& x1) {
  uint32_t ks0 = k0, ks1 = k1, ks2 = k0 ^ k1 ^ 0x1BD11BDAu;
  x0 += ks0; x1 += ks1;
#define TF_RND(r) { x0 += x1; x1 = rotl32(x1, (r)); x1 ^= x0; }
  TF_RND(13) TF_RND(15) TF_RND(26) TF_RND(6)
  x0 += ks1; x1 += ks2 + 1u;
  TF_RND(17) TF_RND(29) TF_RND(16) TF_RND(24)
  x0 += ks2; x1 += ks0 + 2u;
  TF_RND(13) TF_RND(15) TF_RND(26) TF_RND(6)
  x0 += ks0; x1 += ks1 + 3u;
  TF_RND(17) TF_RND(29) TF_RND(16) TF_RND(24)
  x0 += ks1; x1 += ks2 + 4u;
  TF_RND(13) TF_RND(15) TF_RND(26) TF_RND(6)
  x0 += ks2; x1 += ks0 + 5u;
#undef TF_RND
}

__device__ __forceinline__ float2 h2f(uint32_t u) {
  __half2 h = *(__half2*)&u;
  return __half22float2(h);
}

// ---------------- init: out = p (f32), x = p (fp16) ----------------
__global__ void init_kernel(const float* __restrict__ p, uint32_t* __restrict__ xh,
                            float* __restrict__ out, int total4) {
  int t4 = blockIdx.x * blockDim.x + threadIdx.x;
  if (t4 >= total4) return;
  fx4 v = __builtin_nontemporal_load((const fx4*)p + t4);
  __builtin_nontemporal_store(v, (fx4*)out + t4);
  __half2 h0 = __floats2half2_rn(v.x, v.y);
  __half2 h1 = __floats2half2_rn(v.z, v.w);
  ux2 u;
  u.x = *(const uint32_t*)&h0;
  u.y = *(const uint32_t*)&h1;
  __builtin_nontemporal_store(u, (ux2*)xh + t4);
}

// ---------------- CSR build: fused per-row histogram (both matrices) ----------------
__global__ void hist_both(const int* __restrict__ t_row, int nnz_t,
                          const int* __restrict__ s_row, int nnz_s,
                          int* __restrict__ cnt, int H) {
  int e = blockIdx.x * blockDim.x + threadIdx.x;
  if (e < nnz_t) {
    atomicAdd(&cnt[t_row[e]], 1);
  } else if (e < nnz_t + nnz_s) {
    atomicAdd(&cnt[H + s_row[e - nnz_t]], 1);
  }
}

// ---------------- hierarchical exclusive scan ----------------
__global__ void scan_block(int* __restrict__ data, int* __restrict__ partials, int len) {
  int base = blockIdx.x * 2048 + threadIdx.x * 8;
  int v[8];
#pragma unroll
  for (int k = 0; k < 8; ++k) { int i = base + k; v[k] = (i < len) ? data[i] : 0; }
  int tsum = 0;
#pragma unroll
  for (int k = 0; k < 8; ++k) { int tv = v[k]; v[k] = tsum; tsum += tv; }
  int lane = threadIdx.x & 63, wid = threadIdx.x >> 6;
  int inc = tsum;
  for (int off = 1; off < 64; off <<= 1) {
    int up = __shfl_up(inc, off, 64);
    if (lane >= off) inc += up;
  }
  __shared__ int wsum[4];
  if (lane == 63) wsum[wid] = inc;
  __syncthreads();
  int wbase = 0;
  for (int w = 0; w < wid; ++w) wbase += wsum[w];
  int texc = wbase + inc - tsum;
#pragma unroll
  for (int k = 0; k < 8; ++k) { int i = base + k; if (i < len) data[i] = texc + v[k]; }
  if (threadIdx.x == 255) partials[blockIdx.x] = texc + tsum;
}

__global__ void scan_top(int* __restrict__ p, int n) {
  __shared__ int sdata[1024];
  __shared__ int carry_s;
  int tid = threadIdx.x;
  if (tid == 0) carry_s = 0;
  __syncthreads();
  for (int base = 0; base < n; base += 1024) {
    int i = base + tid;
    int v = (i < n) ? p[i] : 0;
    sdata[tid] = v;
    __syncthreads();
    for (int off = 1; off < 1024; off <<= 1) {
      int tmp = (tid >= off) ? sdata[tid - off] : 0;
      __syncthreads();
      sdata[tid] += tmp;
      __syncthreads();
    }
    int c = carry_s;
    if (i < n) p[i] = c + sdata[tid] - v;
    __syncthreads();
    if (tid == 1023) carry_s = c + sdata[1023];
    __syncthreads();
  }
}

__global__ void scan_addback(int* __restrict__ data, const int* __restrict__ partials, int len) {
  int base = blockIdx.x * 2048 + threadIdx.x * 8;
  int add = partials[blockIdx.x];
#pragma unroll
  for (int k = 0; k < 8; ++k) { int i = base + k; if (i < len) data[i] += add; }
}

// ---------------- fused scatter (cursor = offs itself; post-scatter offs[g]=row end) ----
__global__ void scatter_both(const int* __restrict__ t_row, const int* __restrict__ t_col,
                             const float* __restrict__ t_val, int nnz_t,
                             const int* __restrict__ s_row, const int* __restrict__ s_col,
                             const float* __restrict__ s_val, int nnz_s,
                             int* __restrict__ offs, int2* __restrict__ epack, int H) {
  int e = blockIdx.x * blockDim.x + threadIdx.x;
  if (e < nnz_t) {
    int pos = atomicAdd(&offs[t_row[e]], 1);
    epack[pos] = make_int2(t_col[e], __float_as_int(t_val[e]));
  } else if (e < nnz_t + nnz_s) {
    int i = e - nnz_t;
    int pos = atomicAdd(&offs[H + s_row[i]], 1);
    epack[pos] = make_int2(s_col[i], __float_as_int(s_val[i]));
  }
}

// ---------------- gather SpMM: one wave per row, full D, 8B/lane ----------------
#define GATHER_BODY(SRC)                                                        \
  float4 acc = make_float4(0.f, 0.f, 0.f, 0.f);                                 \
  const ix2* epv = (const ix2*)ep;                                              \
  int i = b;                                                                    \
  for (; i + 7 < e; i += 8) {                                                   \
    ix2 E[8]; uint2 A[8];                                                       \
    _Pragma("unroll")                                                           \
    for (int k = 0; k < 8; ++k) E[k] = __builtin_nontemporal_load(epv + i + k); \
    _Pragma("unroll")                                                           \
    for (int k = 0; k < 8; ++k) A[k] = SRC[(size_t)E[k].x * 64 + lane];         \
    _Pragma("unroll")                                                           \
    for (int k = 0; k < 8; ++k) {                                               \
      float v = __int_as_float(E[k].y);                                         \
      float2 f0 = h2f(A[k].x), f1 = h2f(A[k].y);                                \
      acc.x += v * f0.x; acc.y += v * f0.y;                                     \
      acc.z += v * f1.x; acc.w += v * f1.y;                                     \
    }                                                                           \
  }                                                                             \
  for (; i < e; ++i) {                                                          \
    ix2 E0 = __builtin_nontemporal_load(epv + i);                               \
    uint2 A0 = SRC[(size_t)E0.x * 64 + lane];                                   \
    float v = __int_as_float(E0.y);                                             \
    float2 f0 = h2f(A0.x), f1 = h2f(A0.y);                                      \
    acc.x += v * f0.x; acc.y += v * f0.y;                                       \
    acc.z += v * f1.x; acc.w += v * f1.y;                                       \
  }

__global__ __launch_bounds__(256) void spmm_full(
    const int* __restrict__ offs, const int2* __restrict__ ep,
    const uint2* __restrict__ X, uint2* __restrict__ Y, int nrows, int grow_base) {
  int wid = threadIdx.x >> 6, lane = threadIdx.x & 63;
  int r = blockIdx.x * 4 + wid;
  if (r >= nrows) return;
  int g = grow_base + r;
  int b = (g == 0) ? 0 : offs[g - 1];
  int e = offs[g];
  GATHER_BODY(X)
  __half2 o0 = __floats2half2_rn(acc.x, acc.y);
  __half2 o1 = __floats2half2_rn(acc.z, acc.w);
  uint2 o;
  o.x = *(const uint32_t*)&o0;
  o.y = *(const uint32_t*)&o1;
  Y[(size_t)r * 64 + lane] = o;
}

// ---------------- gather SpMM + residual + dropout + mean-accumulate ----------------
__global__ __launch_bounds__(256) void spmm_drop_full(
    const int* __restrict__ offs, const int2* __restrict__ ep,
    const uint2* __restrict__ T, uint2* __restrict__ x, float* __restrict__ out,
    uint32_t k0, uint32_t k1, int nrows, int grow_base, int is_final) {
  int wid = threadIdx.x >> 6, lane = threadIdx.x & 63;
  int r = blockIdx.x * 4 + wid;
  if (r >= nrows) return;
  int g = grow_base + r;
  int b = (g == 0) ? 0 : offs[g - 1];
  int e = offs[g];
  GATHER_BODY(T)
  size_t xi = (size_t)r * 64 + lane;
  ux2 xv_u = __builtin_nontemporal_load((const ux2*)x + xi);
  float2 x0 = h2f(xv_u.x), x1 = h2f(xv_u.y);
  float h[4] = {acc.x + x0.x, acc.y + x0.y, acc.z + x1.x, acc.w + x1.y};
  int j0 = r * DD + lane * 4;
  float xn[4];
#pragma unroll
  for (int k = 0; k < 4; ++k) {
    uint32_t r0 = 0u, r1 = (uint32_t)(j0 + k);
    tf2x32(k0, k1, r0, r1);
    uint32_t bits = r0 ^ r1;
    float u = __uint_as_float((bits >> 9) | 0x3f800000u) - 1.0f;
    xn[k] = (u < 0.9f) ? h[k] * (1.0f / 0.9f) : 0.0f;
  }
  __half2 nx0 = __floats2half2_rn(xn[0], xn[1]);
  __half2 nx1 = __floats2half2_rn(xn[2], xn[3]);
  ux2 nxu;
  nxu.x = *(const uint32_t*)&nx0;
  nxu.y = *(const uint32_t*)&nx1;
  __builtin_nontemporal_store(nxu, (ux2*)x + xi);
  fx4 ov = __builtin_nontemporal_load((const fx4*)out + xi);
  ov.x += xn[0]; ov.y += xn[1]; ov.z += xn[2]; ov.w += xn[3];
  if (is_final) { ov.x *= 0.25f; ov.y *= 0.25f; ov.z *= 0.25f; ov.w *= 0.25f; }
  __builtin_nontemporal_store(ov, (fx4*)out + xi);
}

extern "C" void kernel_launch(void* const* d_in, const int* in_sizes, int n_in,
                              void* d_out, int out_size, void* d_ws, size_t ws_size,
                              hipStream_t stream) {
  const float* p     = (const float*)d_in[0];
  const int*   s_row = (const int*)d_in[1];
  const int*   s_col = (const int*)d_in[2];
  const float* s_val = (const float*)d_in[3];
  const int*   t_row = (const int*)d_in[4];
  const int*   t_col = (const int*)d_in[5];
  const float* t_val = (const float*)d_in[6];

  const int nnz_s = in_sizes[1];
  const int nnz_t = in_sizes[4];
  const int N = in_sizes[0] / DD;   // 50000 pois
  const int H = 50000;              // num_hyperedges (problem constant)

  // ---- workspace carve ----
  uint2* xh    = (uint2*)d_ws;                           // [N*64] (4 halves each)
  uint2* th    = xh + (size_t)N * 64;                    // [H*64]
  int2*  epack = (int2*)(th + (size_t)H * 64);           // [nnz_t + nnz_s]
  int*   offs  = (int*)(epack + (size_t)nnz_t + nnz_s);  // [H+N] (t rows then s rows)
  const int slots = H + N;
  int*   part  = offs + slots;

  float* out = (float*)d_out;

  // ---- CSR build (both matrices share one offset table) ----
  (void)hipMemsetAsync(offs, 0, sizeof(int) * (size_t)slots, stream);
  const int nnz_all = nnz_t + nnz_s;
  const int hb = (nnz_all + 255) / 256;
  hist_both<<<hb, 256, 0, stream>>>(t_row, nnz_t, s_row, nnz_s, offs, H);
  const int nscan_blocks = (slots + 2047) / 2048;
  scan_block<<<nscan_blocks, 256, 0, stream>>>(offs, part, slots);
  scan_top<<<1, 1024, 0, stream>>>(part, nscan_blocks);
  scan_addback<<<nscan_blocks, 256, 0, stream>>>(offs, part, slots);
  scatter_both<<<hb, 256, 0, stream>>>(t_row, t_col, t_val, nnz_t,
                                       s_row, s_col, s_val, nnz_s, offs, epack, H);

  // ---- init ----
  const int total4 = N * DD / 4;
  init_kernel<<<(total4 + 255) / 256, 256, 0, stream>>>(p, (uint32_t*)xh, out, total4);

  // ---- 3 layers ----
  for (int i = 0; i < 3; ++i) {
    spmm_full<<<(H + 3) / 4, 256, 0, stream>>>(offs, epack, xh, th, H, 0);
    uint32_t x0 = 0u, x1 = (uint32_t)i;
    tf2x32(0u, 42u, x0, x1);
    spmm_drop_full<<<(N + 3) / 4, 256, 0, stream>>>(offs, epack, th, xh, out,
                                                    x0, x1, N, H, i == 2);
  }
}

// Round 7
// 854.229 us; speedup vs baseline: 37.5002x; 1.3213x over previous
//
#include <hip/hip_runtime.h>
#include <hip/hip_fp16.h>
#include <stdint.h>

#define DD 256
#define BK_SHIFT 10
#define NB 98            // ceil(100000/1024) buckets of 1024 slots
#define CHUNK 4096       // edges per coarse-scatter block

// ext_vector types accepted by __builtin_nontemporal_*
typedef float    fx4 __attribute__((ext_vector_type(4)));
typedef uint32_t ux2 __attribute__((ext_vector_type(2)));

// ---------------- Threefry-2x32 (bit-exact JAX) ----------------
__host__ __device__ __forceinline__ uint32_t rotl32(uint32_t v, int r) {
  return (v << r) | (v >> (32 - r));
}

__host__ __device__ inline void tf2x32(uint32_t k0, uint32_t k1,
                                       uint32_t& x0, uint32_t& x1) {
  uint32_t ks0 = k0, ks1 = k1, ks2 = k0 ^ k1 ^ 0x1BD11BDAu;
  x0 += ks0; x1 += ks1;
#define TF_RND(r) { x0 += x1; x1 = rotl32(x1, (r)); x1 ^= x0; }
  TF_RND(13) TF_RND(15) TF_RND(26) TF_RND(6)
  x0 += ks1; x1 += ks2 + 1u;
  TF_RND(17) TF_RND(29) TF_RND(16) TF_RND(24)
  x0 += ks2; x1 += ks0 + 2u;
  TF_RND(13) TF_RND(15) TF_RND(26) TF_RND(6)
  x0 += ks0; x1 += ks1 + 3u;
  TF_RND(17) TF_RND(29) TF_RND(16) TF_RND(24)
  x0 += ks1; x1 += ks2 + 4u;
  TF_RND(13) TF_RND(15) TF_RND(26) TF_RND(6)
  x0 += ks2; x1 += ks0 + 5u;
#undef TF_RND
}

__device__ __forceinline__ float2 h2f(uint32_t u) {
  __half2 h = *(__half2*)&u;
  return __half22float2(h);
}

// ---------------- init: out = p (f32), x = p (fp16) ----------------
__global__ void init_kernel(const float* __restrict__ p, uint32_t* __restrict__ xh,
                            float* __restrict__ out, int total4) {
  int t4 = blockIdx.x * blockDim.x + threadIdx.x;
  if (t4 >= total4) return;
  fx4 v = __builtin_nontemporal_load((const fx4*)p + t4);
  __builtin_nontemporal_store(v, (fx4*)out + t4);
  __half2 h0 = __floats2half2_rn(v.x, v.y);
  __half2 h1 = __floats2half2_rn(v.z, v.w);
  ux2 u;
  u.x = *(const uint32_t*)&h0;
  u.y = *(const uint32_t*)&h1;
  __builtin_nontemporal_store(u, (ux2*)xh + t4);
}

// ---------------- K1: bucket histogram (LDS-aggregated) ----------------
__global__ __launch_bounds__(256) void bucket_hist(
    const int* __restrict__ t_row, int nnz_t,
    const int* __restrict__ s_row, int nnz_s,
    int* __restrict__ gbcnt, int H) {
  __shared__ int lcnt[NB];
  for (int i = threadIdx.x; i < NB; i += 256) lcnt[i] = 0;
  __syncthreads();
  const int base = blockIdx.x * CHUNK;
  const int nnz_all = nnz_t + nnz_s;
#pragma unroll
  for (int k = 0; k < CHUNK / 256; ++k) {
    int e = base + k * 256 + threadIdx.x;
    if (e < nnz_all) {
      int slot = (e < nnz_t) ? t_row[e] : (H + s_row[e - nnz_t]);
      atomicAdd(&lcnt[slot >> BK_SHIFT], 1);
    }
  }
  __syncthreads();
  for (int i = threadIdx.x; i < NB; i += 256)
    if (lcnt[i]) atomicAdd(&gbcnt[i], lcnt[i]);
}

// ---------------- K2: bucket scan + cursor init ----------------
__global__ void bucket_scan(const int* __restrict__ gbcnt,
                            int* __restrict__ bbase, int* __restrict__ gcur) {
  if (threadIdx.x == 0) {
    int run = 0;
    for (int i = 0; i < NB; ++i) { bbase[i] = run; gcur[i] = run; run += gbcnt[i]; }
    bbase[NB] = run;
  }
}

// ---------------- K3: coarse scatter into bucket-major staging ----------------
// record = (slot << 32) | (col16 << 16) | val_fp16
__global__ __launch_bounds__(256) void coarse_scatter(
    const int* __restrict__ t_row, const int* __restrict__ t_col,
    const float* __restrict__ t_val, int nnz_t,
    const int* __restrict__ s_row, const int* __restrict__ s_col,
    const float* __restrict__ s_val, int nnz_s,
    int* __restrict__ gcur, uint64_t* __restrict__ staging, int H) {
  __shared__ int lcnt[NB], lbase[NB], gofs[NB];
  __shared__ int ltotal;
  __shared__ uint64_t stage[CHUNK];
  const int tid = threadIdx.x;
  for (int i = tid; i < NB; i += 256) lcnt[i] = 0;
  __syncthreads();
  const int base = blockIdx.x * CHUNK;
  const int nnz_all = nnz_t + nnz_s;
  uint64_t rec[CHUNK / 256];
#pragma unroll
  for (int k = 0; k < CHUNK / 256; ++k) {
    int e = base + k * 256 + tid;
    if (e < nnz_all) {
      int slot, col; float val;
      if (e < nnz_t) { slot = t_row[e]; col = t_col[e]; val = t_val[e]; }
      else { int i2 = e - nnz_t; slot = H + s_row[i2]; col = s_col[i2]; val = s_val[i2]; }
      uint32_t packed = ((uint32_t)col << 16) |
                        (uint32_t)__half_as_ushort(__float2half_rn(val));
      rec[k] = ((uint64_t)(uint32_t)slot << 32) | packed;
      atomicAdd(&lcnt[slot >> BK_SHIFT], 1);
    } else {
      rec[k] = ~0ull;
    }
  }
  __syncthreads();
  if (tid == 0) {
    int run = 0;
    for (int i = 0; i < NB; ++i) { lbase[i] = run; run += lcnt[i]; }
    ltotal = run;
  }
  __syncthreads();
  // claim global segments (one atomic per non-empty bucket), then reuse lcnt as cursor
  if (tid < NB) {
    if (lcnt[tid]) gofs[tid] = atomicAdd(&gcur[tid], lcnt[tid]);
    lcnt[tid] = 0;
  }
  __syncthreads();
#pragma unroll
  for (int k = 0; k < CHUNK / 256; ++k) {
    int slot = (int)(rec[k] >> 32);
    if (slot >= 0) {  // valid (invalid = 0xFFFFFFFF -> negative)
      int b = slot >> BK_SHIFT;
      int p = atomicAdd(&lcnt[b], 1);
      stage[lbase[b] + p] = rec[k];
    }
  }
  __syncthreads();
  const int tot = ltotal;
  for (int i = tid; i < tot; i += 256) {
    uint64_t r = stage[i];
    int b = (int)(r >> 32) >> BK_SHIFT;
    staging[(size_t)gofs[b] + (i - lbase[b])] = r;
  }
}

// ---------------- K4: fine scatter (one block per bucket, L2-local) ----------------
// Also writes global offs[] (row segment ends) — replaces hist+scan pipeline.
__global__ __launch_bounds__(256) void fine_scatter(
    const uint64_t* __restrict__ staging, const int* __restrict__ bbase,
    int* __restrict__ offs, uint32_t* __restrict__ epk, int slots) {
  __shared__ int scnt[1024];
  __shared__ int sofs[1024];
  __shared__ int wsum[4];
  const int b = blockIdx.x;
  const int bb = bbase[b], be = bbase[b + 1];
  const int tid = threadIdx.x;
  for (int i = tid; i < 1024; i += 256) scnt[i] = 0;
  __syncthreads();
  for (int i = bb + tid; i < be; i += 256)
    atomicAdd(&scnt[(int)(staging[i] >> 32) & 1023], 1);
  __syncthreads();
  // exclusive scan of scnt[1024] -> sofs (4 elems/thread)
  const int base4 = tid * 4;
  int v[4], pre[4];
#pragma unroll
  for (int k = 0; k < 4; ++k) v[k] = scnt[base4 + k];
  int tsum = 0;
#pragma unroll
  for (int k = 0; k < 4; ++k) { pre[k] = tsum; tsum += v[k]; }
  int lane = tid & 63, wv = tid >> 6;
  int inc = tsum;
  for (int off = 1; off < 64; off <<= 1) {
    int up = __shfl_up(inc, off, 64);
    if (lane >= off) inc += up;
  }
  if (lane == 63) wsum[wv] = inc;
  __syncthreads();
  int wbase = 0;
  for (int w = 0; w < wv; ++w) wbase += wsum[w];
  int texc = wbase + inc - tsum;
#pragma unroll
  for (int k = 0; k < 4; ++k) sofs[base4 + k] = texc + pre[k];
  __syncthreads();
  // global row-end offsets
#pragma unroll
  for (int k = 0; k < 4; ++k) {
    int g = (b << BK_SHIFT) + base4 + k;
    if (g < slots) offs[g] = bb + sofs[base4 + k] + v[k];
  }
  __syncthreads();
  // place (random 4B writes within this bucket's ~131KB window -> L2-local)
  for (int i = bb + tid; i < be; i += 256) {
    uint64_t r = staging[i];
    int ls = (int)(r >> 32) & 1023;
    int p = atomicAdd(&sofs[ls], 1);
    epk[(size_t)bb + p] = (uint32_t)r;
  }
}

// ---------------- gather SpMM: one wave per row, full D, packed 4B edges ----------------
#define GATHER_BODY(SRC)                                                          \
  float4 acc = make_float4(0.f, 0.f, 0.f, 0.f);                                   \
  int i = b;                                                                      \
  for (; i + 7 < e; i += 8) {                                                     \
    uint32_t E[8]; uint2 A[8];                                                    \
    _Pragma("unroll")                                                             \
    for (int k = 0; k < 8; ++k) E[k] = __builtin_nontemporal_load(ep + i + k);    \
    _Pragma("unroll")                                                             \
    for (int k = 0; k < 8; ++k) A[k] = SRC[(size_t)(E[k] >> 16) * 64 + lane];     \
    _Pragma("unroll")                                                             \
    for (int k = 0; k < 8; ++k) {                                                 \
      float v = __half2float(__ushort_as_half((unsigned short)(E[k] & 0xFFFFu))); \
      float2 f0 = h2f(A[k].x), f1 = h2f(A[k].y);                                  \
      acc.x += v * f0.x; acc.y += v * f0.y;                                       \
      acc.z += v * f1.x; acc.w += v * f1.y;                                       \
    }                                                                             \
  }                                                                               \
  for (; i < e; ++i) {                                                            \
    uint32_t E0 = __builtin_nontemporal_load(ep + i);                             \
    uint2 A0 = SRC[(size_t)(E0 >> 16) * 64 + lane];                               \
    float v = __half2float(__ushort_as_half((unsigned short)(E0 & 0xFFFFu)));     \
    float2 f0 = h2f(A0.x), f1 = h2f(A0.y);                                        \
    acc.x += v * f0.x; acc.y += v * f0.y;                                         \
    acc.z += v * f1.x; acc.w += v * f1.y;                                         \
  }

__global__ __launch_bounds__(256) void spmm_full(
    const int* __restrict__ offs, const uint32_t* __restrict__ ep,
    const uint2* __restrict__ X, uint2* __restrict__ Y, int nrows, int grow_base) {
  int wid = threadIdx.x >> 6, lane = threadIdx.x & 63;
  int r = blockIdx.x * 4 + wid;
  if (r >= nrows) return;
  int g = grow_base + r;
  int b = (g == 0) ? 0 : offs[g - 1];
  int e = offs[g];
  GATHER_BODY(X)
  __half2 o0 = __floats2half2_rn(acc.x, acc.y);
  __half2 o1 = __floats2half2_rn(acc.z, acc.w);
  uint2 o;
  o.x = *(const uint32_t*)&o0;
  o.y = *(const uint32_t*)&o1;
  Y[(size_t)r * 64 + lane] = o;
}

__global__ __launch_bounds__(256) void spmm_drop_full(
    const int* __restrict__ offs, const uint32_t* __restrict__ ep,
    const uint2* __restrict__ T, uint2* __restrict__ x, float* __restrict__ out,
    uint32_t k0, uint32_t k1, int nrows, int grow_base, int is_final) {
  int wid = threadIdx.x >> 6, lane = threadIdx.x & 63;
  int r = blockIdx.x * 4 + wid;
  if (r >= nrows) return;
  int g = grow_base + r;
  int b = (g == 0) ? 0 : offs[g - 1];
  int e = offs[g];
  GATHER_BODY(T)
  size_t xi = (size_t)r * 64 + lane;
  ux2 xv_u = __builtin_nontemporal_load((const ux2*)x + xi);
  float2 x0 = h2f(xv_u.x), x1 = h2f(xv_u.y);
  float h[4] = {acc.x + x0.x, acc.y + x0.y, acc.z + x1.x, acc.w + x1.y};
  int j0 = r * DD + lane * 4;
  float xn[4];
#pragma unroll
  for (int k = 0; k < 4; ++k) {
    uint32_t r0 = 0u, r1 = (uint32_t)(j0 + k);
    tf2x32(k0, k1, r0, r1);
    uint32_t bits = r0 ^ r1;
    float u = __uint_as_float((bits >> 9) | 0x3f800000u) - 1.0f;
    xn[k] = (u < 0.9f) ? h[k] * (1.0f / 0.9f) : 0.0f;
  }
  __half2 nx0 = __floats2half2_rn(xn[0], xn[1]);
  __half2 nx1 = __floats2half2_rn(xn[2], xn[3]);
  ux2 nxu;
  nxu.x = *(const uint32_t*)&nx0;
  nxu.y = *(const uint32_t*)&nx1;
  __builtin_nontemporal_store(nxu, (ux2*)x + xi);
  fx4 ov = __builtin_nontemporal_load((const fx4*)out + xi);
  ov.x += xn[0]; ov.y += xn[1]; ov.z += xn[2]; ov.w += xn[3];
  if (is_final) { ov.x *= 0.25f; ov.y *= 0.25f; ov.z *= 0.25f; ov.w *= 0.25f; }
  __builtin_nontemporal_store(ov, (fx4*)out + xi);
}

extern "C" void kernel_launch(void* const* d_in, const int* in_sizes, int n_in,
                              void* d_out, int out_size, void* d_ws, size_t ws_size,
                              hipStream_t stream) {
  const float* p     = (const float*)d_in[0];
  const int*   s_row = (const int*)d_in[1];
  const int*   s_col = (const int*)d_in[2];
  const float* s_val = (const float*)d_in[3];
  const int*   t_row = (const int*)d_in[4];
  const int*   t_col = (const int*)d_in[5];
  const float* t_val = (const float*)d_in[6];

  const int nnz_s = in_sizes[1];
  const int nnz_t = in_sizes[4];
  const int N = in_sizes[0] / DD;   // 50000 pois
  const int H = 50000;              // num_hyperedges (problem constant)
  const int slots = H + N;
  const int nnz_all = nnz_t + nnz_s;

  // ---- workspace carve (8B-aligned first) ----
  uint2*    xh      = (uint2*)d_ws;                        // [N*64]  25.6 MB
  uint2*    th      = xh + (size_t)N * 64;                 // [H*64]  25.6 MB
  uint64_t* staging = (uint64_t*)(th + (size_t)H * 64);    // [nnz_all] 25.6 MB
  uint32_t* epk     = (uint32_t*)(staging + nnz_all);      // [nnz_all] 12.8 MB
  int*      offs    = (int*)(epk + nnz_all);               // [slots]
  int*      gbcnt   = offs + slots;                        // [NB]
  int*      bbase   = gbcnt + NB;                          // [NB+1]
  int*      gcur    = bbase + (NB + 1);                    // [NB]

  float* out = (float*)d_out;

  // ---- build bucket-partitioned packed CSR ----
  (void)hipMemsetAsync(gbcnt, 0, sizeof(int) * NB, stream);
  const int cblocks = (nnz_all + CHUNK - 1) / CHUNK;
  bucket_hist<<<cblocks, 256, 0, stream>>>(t_row, nnz_t, s_row, nnz_s, gbcnt, H);
  bucket_scan<<<1, 64, 0, stream>>>(gbcnt, bbase, gcur);
  coarse_scatter<<<cblocks, 256, 0, stream>>>(t_row, t_col, t_val, nnz_t,
                                              s_row, s_col, s_val, nnz_s,
                                              gcur, staging, H);
  fine_scatter<<<NB, 256, 0, stream>>>(staging, bbase, offs, epk, slots);

  // ---- init ----
  const int total4 = N * DD / 4;
  init_kernel<<<(total4 + 255) / 256, 256, 0, stream>>>(p, (uint32_t*)xh, out, total4);

  // ---- 3 layers ----
  for (int i = 0; i < 3; ++i) {
    spmm_full<<<(H + 3) / 4, 256, 0, stream>>>(offs, epk, xh, th, H, 0);
    uint32_t x0 = 0u, x1 = (uint32_t)i;
    tf2x32(0u, 42u, x0, x1);
    spmm_drop_full<<<(N + 3) / 4, 256, 0, stream>>>(offs, epk, th, xh, out,
                                                    x0, x1, N, H, i == 2);
  }
}